// Round 8
// baseline (3215.318 us; speedup 1.0000x reference)
//
#include <hip/hip_runtime.h>
#include <stdint.h>

// ---------------------------------------------------------------------------
// LSTM time-series predictor, persistent kernel, R8: BARRIER-FREE DATAFLOW.
// 8 batch-groups x 32 WGs (g = blockIdx&7, w = blockIdx>>3), agent-scope
// (sc1/MALL) transport as proven in R4/R7. NO grid barriers: every h u64
// (4 bf16) embeds a 2-bit phase tag in the low mantissa bits of ushorts 0,2
// (writer rounds to nearest bf16 with forced parity => max err 1 ulp@6bit).
// Readers poll the data itself: tag==phase+1 (mod 4) => valid. Triple-
// buffered h slots (overwrite-safe by induction: writer at phase p implies
// all WGs finished reading p-2). Intra-WG sync via raw lgkmcnt+s_barrier
// (no vmcnt drain => h stores fully async). Chain: 2 MALL hops, not 4.
// Weights: W_hh0/W_ih1 in LDS fragment-major; W_hh1/W_ih0/Wcomb in VGPRs.
// Decoder folded (R7): 2 phases/step, fc fused into phase A via Wcomb.
// ---------------------------------------------------------------------------

#define NWG 256
#define NTH 256

constexpr int Tt = 512, TGT = 96;

typedef __attribute__((ext_vector_type(8))) short bf16x8;
typedef __attribute__((ext_vector_type(4))) float f32x4;
typedef unsigned long long u64;

__device__ __forceinline__ unsigned short f2bf(float f) {
  union { float f; unsigned u; } v; v.f = f;
  return (unsigned short)((v.u + 0x7fffu + ((v.u >> 16) & 1u)) >> 16);
}
__device__ __forceinline__ float bf2f(unsigned short h) {
  union { unsigned u; float f; } v; v.u = ((unsigned)h) << 16; return v.f;
}
// nearest bf16 with bit0 forced to `bit` (tag embedding)
__device__ __forceinline__ unsigned short f2bf_tag(float f, unsigned bit) {
  unsigned short b = f2bf(f);
  if ((b ^ bit) & 1) {
    if ((b & 0x7fff) == 0) b = (unsigned short)(b | 1);    // +-0 -> smallest odd
    else {
      unsigned short ca = (unsigned short)(b - 1), cb = (unsigned short)(b + 1);
      b = (fabsf(f - bf2f(ca)) <= fabsf(f - bf2f(cb))) ? ca : cb;
    }
  }
  return b;
}
__device__ __forceinline__ float sigm(float x) { return 1.f / (1.f + __expf(-x)); }
__device__ __forceinline__ float tanh_(float x) { return 1.f - 2.f / (__expf(2.f * x) + 1.f); }

__device__ __forceinline__ u64 ald64a(const u64* p) {
  return __hip_atomic_load(p, __ATOMIC_RELAXED, __HIP_MEMORY_SCOPE_AGENT);
}
__device__ __forceinline__ void ast64a(u64* p, u64 v) {
  __hip_atomic_store(p, v, __ATOMIC_RELAXED, __HIP_MEMORY_SCOPE_AGENT);
}
__device__ __forceinline__ unsigned tag_of(u64 v) {
  return ((unsigned)v & 1u) | ((((unsigned)(v >> 32)) & 1u) << 1);
}

// intra-WG barrier WITHOUT vmcnt drain (LDS-only ordering)
__device__ __forceinline__ void wgbar() {
  asm volatile("s_waitcnt lgkmcnt(0)\n\ts_barrier" ::: "memory");
}

struct SMem {
  unsigned short wB[2][4][16][64][8]; // 128 KiB: [whh0|wih1][wave][kc][lane][8]
  u64 a0[16 * 68];                    // 8.5 KiB staged A: [kc][b*8 + k8&7]
  u64 a1[16 * 68];                    // 8.5 KiB
  unsigned short wfc2[1024];          // 2 KiB: W_fc rows w*2, w*2+1 (bf16)
  float gpart[4][272];                // per-wave D staging (wave-local)
  float fcp[256];                     // fc partials
  float b0s[64], b1s[64], b0d[64], bfc2[2];
};

__device__ __forceinline__ int amap(int idx) {
  int b = idx >> 7, k8 = idx & 127;
  return (k8 >> 3) * 68 + b * 8 + (k8 & 7);
}

__device__ __forceinline__ u64 polllead(const u64* p, unsigned tg) {
  u64 v = ald64a(p);
  while (tag_of(v) != tg) { __builtin_amdgcn_s_sleep(2); v = ald64a(p); }
  return v;
}
__device__ __forceinline__ u64 pollsib(const u64* p, unsigned tg, u64 v) {
  while (tag_of(v) != tg) { __builtin_amdgcn_s_sleep(1); v = ald64a(p); }
  return v;
}

// stage one matrix (4 u64/thread) with tag polling
__device__ __forceinline__ void pollstage1(u64* dst, const u64* src, unsigned tg, int tid) {
  const u64* p = src + tid;
  u64 v0 = polllead(p, tg);
  u64 v1 = ald64a(p + 256), v2 = ald64a(p + 512), v3 = ald64a(p + 768);
  v1 = pollsib(p + 256, tg, v1);
  v2 = pollsib(p + 512, tg, v2);
  v3 = pollsib(p + 768, tg, v3);
  dst[amap(tid)] = v0; dst[amap(tid + 256)] = v1;
  dst[amap(tid + 512)] = v2; dst[amap(tid + 768)] = v3;
}
__device__ __forceinline__ void pollstage2(u64* d0, const u64* s0, unsigned tg0,
                                           u64* d1, const u64* s1, unsigned tg1, int tid) {
  const u64 *p0 = s0 + tid, *p1 = s1 + tid;
  u64 a = ald64a(p0), b = ald64a(p1);
  a = pollsib(p0, tg0, a);          // lead spins (both issued together)
  b = pollsib(p1, tg1, b);
  u64 a1 = ald64a(p0 + 256), a2 = ald64a(p0 + 512), a3 = ald64a(p0 + 768);
  u64 b1 = ald64a(p1 + 256), b2 = ald64a(p1 + 512), b3 = ald64a(p1 + 768);
  a1 = pollsib(p0 + 256, tg0, a1); a2 = pollsib(p0 + 512, tg0, a2); a3 = pollsib(p0 + 768, tg0, a3);
  b1 = pollsib(p1 + 256, tg1, b1); b2 = pollsib(p1 + 512, tg1, b2); b3 = pollsib(p1 + 768, tg1, b3);
  d0[amap(tid)] = a;  d0[amap(tid + 256)] = a1;
  d0[amap(tid + 512)] = a2; d0[amap(tid + 768)] = a3;
  d1[amap(tid)] = b;  d1[amap(tid + 256)] = b1;
  d1[amap(tid + 512)] = b2; d1[amap(tid + 768)] = b3;
}

#define MFMA(a, b, c) __builtin_amdgcn_mfma_f32_16x16x32_bf16(a, b, c, 0, 0, 0)

__global__ __launch_bounds__(NTH, 1) void lstm_kernel(
    const float* __restrict__ x,
    const float* __restrict__ Wih0, const float* __restrict__ Whh0,
    const float* __restrict__ bih0, const float* __restrict__ bhh0,
    const float* __restrict__ Wih1, const float* __restrict__ Whh1,
    const float* __restrict__ bih1, const float* __restrict__ bhh1,
    const float* __restrict__ Wfc, const float* __restrict__ bfc,
    u64* h0q, u64* h1q, float* __restrict__ out)
{
  __shared__ SMem sm;
  const int g = blockIdx.x & 7;
  const int wgw = blockIdx.x >> 3;
  const int tid = threadIdx.x;

  // ---- weight staging (fragment-major, conflict-free reads) ----
  for (int e = tid; e < 8192; e += NTH) {
    int m = e >> 12, w4 = (e >> 10) & 3, kc = (e >> 6) & 15, l = e & 63;
    int colx = l & 15, qx = l >> 4;
    size_t row = (size_t)((colx & 3) * 512 + wgw * 16 + w4 * 4 + (colx >> 2));
    const float* src = (m ? Wih1 : Whh0) + row * 512 + kc * 32 + qx * 8;
    unsigned short* dst = &sm.wB[m][w4][kc][l][0];
    float4 u = *(const float4*)src, v = *(const float4*)(src + 4);
    dst[0] = f2bf(u.x); dst[1] = f2bf(u.y); dst[2] = f2bf(u.z); dst[3] = f2bf(u.w);
    dst[4] = f2bf(v.x); dst[5] = f2bf(v.y); dst[6] = f2bf(v.z); dst[7] = f2bf(v.w);
  }
  for (int e = tid; e < 1024; e += NTH)
    sm.wfc2[e] = f2bf(Wfc[(size_t)(wgw * 2 + (e >> 9)) * 512 + (e & 511)]);
  if (tid < 64) {
    int jj = tid >> 2, g4 = tid & 3;
    int grow = g4 * 512 + wgw * 16 + jj;
    float s0 = bih0[grow] + bhh0[grow];
    sm.b0s[tid] = s0;
    sm.b1s[tid] = bih1[grow] + bhh1[grow];
    float ex = 0.f;
    for (int i = 0; i < 64; ++i) ex += Wih0[(size_t)grow * 64 + i] * bfc[i];
    sm.b0d[tid] = s0 + ex;
  }
  if (tid < 2) sm.bfc2[tid] = bfc[wgw * 2 + tid];

  // ---- per-lane constants ----
  const int wave = tid >> 6, lane = tid & 63;
  const int col = lane & 15, quad = lane >> 4;
  const int koff = quad * 8;
  const size_t rowg = (size_t)((col & 3) * 512 + wgw * 16 + wave * 4 + (col >> 2));

  // ---- register B-fragments: W_hh1, W_ih0, Wcomb = Wih0 @ Wfc ----
  bf16x8 whh1f[16];
#pragma unroll
  for (int kc = 0; kc < 16; ++kc) {
    const float* p = Whh1 + rowg * 512 + kc * 32 + koff;
    float4 u = *(const float4*)p, v = *(const float4*)(p + 4);
    bf16x8 r;
    r[0] = (short)f2bf(u.x); r[1] = (short)f2bf(u.y); r[2] = (short)f2bf(u.z); r[3] = (short)f2bf(u.w);
    r[4] = (short)f2bf(v.x); r[5] = (short)f2bf(v.y); r[6] = (short)f2bf(v.z); r[7] = (short)f2bf(v.w);
    whh1f[kc] = r;
  }
  bf16x8 wih0f[2];
#pragma unroll
  for (int kc = 0; kc < 2; ++kc) {
    const float* p = Wih0 + rowg * 64 + kc * 32 + koff;
    float4 u = *(const float4*)p, v = *(const float4*)(p + 4);
    bf16x8 r;
    r[0] = (short)f2bf(u.x); r[1] = (short)f2bf(u.y); r[2] = (short)f2bf(u.z); r[3] = (short)f2bf(u.w);
    r[4] = (short)f2bf(v.x); r[5] = (short)f2bf(v.y); r[6] = (short)f2bf(v.z); r[7] = (short)f2bf(v.w);
    wih0f[kc] = r;
  }
  bf16x8 wcombf[16];
  {
    float wc[16][8];
#pragma unroll
    for (int kc = 0; kc < 16; ++kc)
#pragma unroll
      for (int j = 0; j < 8; ++j) wc[kc][j] = 0.f;
    for (int i = 0; i < 64; ++i) {
      float wi = Wih0[rowg * 64 + i];
      const float* fr = Wfc + (size_t)i * 512 + koff;
#pragma unroll
      for (int kc = 0; kc < 16; ++kc) {
        float4 u = *(const float4*)(fr + kc * 32);
        float4 v = *(const float4*)(fr + kc * 32 + 4);
        wc[kc][0] += wi * u.x; wc[kc][1] += wi * u.y;
        wc[kc][2] += wi * u.z; wc[kc][3] += wi * u.w;
        wc[kc][4] += wi * v.x; wc[kc][5] += wi * v.y;
        wc[kc][6] += wi * v.z; wc[kc][7] += wi * v.w;
      }
    }
#pragma unroll
    for (int kc = 0; kc < 16; ++kc) {
      bf16x8 r;
#pragma unroll
      for (int j = 0; j < 8; ++j) r[j] = (short)f2bf(wc[kc][j]);
      wcombf[kc] = r;
    }
  }
  __syncthreads();

  const float b0c = sm.b0s[wave * 16 + col];
  const float b1c = sm.b1s[wave * 16 + col];
  const float b0dc = sm.b0d[wave * 16 + col];
  const unsigned short* pw0 = &sm.wB[0][wave][0][lane][0];   // + kc*512
  const unsigned short* pw1 = &sm.wB[1][wave][0][lane][0];
  const u64* afrag0 = sm.a0 + (col & 7) * 8 + quad * 2;      // + kc*68
  const u64* afrag1 = sm.a1 + (col & 7) * 8 + quad * 2;
  float c0 = 0.f, c1 = 0.f;
  const size_t xstride = (size_t)Tt * 64;
  const int gbase = g * 1024;

  auto loadx = [&](const float* p) -> bf16x8 {
    float4 u = *(const float4*)p, v = *(const float4*)(p + 4);
    bf16x8 r;
    r[0] = (short)f2bf(u.x); r[1] = (short)f2bf(u.y); r[2] = (short)f2bf(u.z); r[3] = (short)f2bf(u.w);
    r[4] = (short)f2bf(v.x); r[5] = (short)f2bf(v.y); r[6] = (short)f2bf(v.z); r[7] = (short)f2bf(v.w);
    return r;
  };

  // D -> activations -> c update -> tagged h store (async, no drain)
  auto actstore = [&](f32x4 v, float& cst, u64* hdst, unsigned tag) {
    float* gp = sm.gpart[wave];
#pragma unroll
    for (int r = 0; r < 4; ++r) gp[(quad * 4 + r) * 17 + col] = v[r];
    unsigned hbits = 0;
    int b = lane >> 2, j = lane & 3;
    if (lane < 32) {
      const float* ro = gp + b * 17 + j * 4;
      float iv = sigm(ro[0]), fv = sigm(ro[1]), gv = tanh_(ro[2]), ov = sigm(ro[3]);
      float c = fv * cst + iv * gv; cst = c;
      float hval = ov * tanh_(c);
      if (j == 0)      hbits = f2bf_tag(hval, tag & 1);
      else if (j == 2) hbits = f2bf_tag(hval, (tag >> 1) & 1);
      else             hbits = f2bf(hval);
    }
    unsigned h1b = __shfl(hbits, (lane + 1) & 63);
    unsigned h2b = __shfl(hbits, (lane + 2) & 63);
    unsigned h3b = __shfl(hbits, (lane + 3) & 63);
    if (lane < 32 && j == 0) {
      u64 pk = (u64)hbits | ((u64)h1b << 16) | ((u64)h2b << 32) | ((u64)h3b << 48);
      ast64a(hdst + b * 128 + wgw * 4 + wave, pk);
    }
  };

  auto fcpart = [&](const u64* asrc) {
    int ks = tid >> 4, b = (tid >> 1) & 7, cc = tid & 1;
    const unsigned short* hr = (const unsigned short*)(asrc + ks * 68 + b * 8);
    const unsigned short* wp = sm.wfc2 + cc * 512 + ks * 32;
    float s = 0.f;
#pragma unroll
    for (int k2 = 0; k2 < 4; ++k2) {
      bf16x8 hv = *(const bf16x8*)(hr + k2 * 8);
      bf16x8 wv = *(const bf16x8*)(wp + k2 * 8);
#pragma unroll
      for (int q2 = 0; q2 < 8; ++q2) s += bf2f((unsigned short)hv[q2]) * bf2f((unsigned short)wv[q2]);
    }
    sm.fcp[tid] = s;
  };
  auto fcout = [&](int d) {
    if (tid < 16) {
      float sv = sm.bfc2[tid & 1];
#pragma unroll
      for (int k = 0; k < 16; ++k) sv += sm.fcp[k * 16 + tid];
      int bb = tid >> 1, cc = tid & 1;
      out[(size_t)(g * 8 + bb) * (TGT * 64) + d * 64 + (wgw * 2 + cc)] = sv;
    }
  };

  // ============ encoder: t = 0..512, layer1 lags by 1 ============
  // h0 phase t: slot t%3, tag (t+1)&3. h1 phase s: slot s%3, tag (s+1)&3.
  for (int t = 0; t <= Tt; ++t) {
    bf16x8 xa0, xa1;
    if (t < Tt) {
      const float* xb = x + (size_t)(g * 8 + (col & 7)) * xstride + (size_t)t * 64 + koff;
      xa0 = loadx(xb); xa1 = loadx(xb + 32);
    }
    if (t == 1) {
      wgbar();
      pollstage1(sm.a0, h0q + 0 * 8192 + gbase, 1u, tid);          // h0_0
      wgbar();
    } else if (t >= 2) {
      wgbar();
      pollstage2(sm.a0, h0q + ((t - 1) % 3) * 8192 + gbase, (unsigned)(t & 3),
                 sm.a1, h1q + ((t - 2) % 3) * 8192 + gbase, (unsigned)((t - 1) & 3), tid);
      wgbar();
    }

    u64* h0cur = h0q + (t % 3) * 8192 + gbase;
    u64* h1cur = h1q + ((t - 1 + 3) % 3) * 8192 + gbase;
    unsigned tg0 = (unsigned)((t + 1) & 3), tg1 = (unsigned)(t & 3);

    if (t < Tt) {
      f32x4 za = {b0c, b0c, b0c, b0c}, zb = {0.f, 0.f, 0.f, 0.f};
      za = MFMA(xa0, wih0f[0], za);
      zb = MFMA(xa1, wih0f[1], zb);
      if (t >= 1) {
        f32x4 ya = {b1c, b1c, b1c, b1c}, yb = {0.f, 0.f, 0.f, 0.f};
#pragma unroll
        for (int kc = 0; kc < 16; ++kc) {
          bf16x8 a = *(const bf16x8*)(afrag0 + kc * 68);
          bf16x8 w0 = *(const bf16x8*)(pw0 + kc * 512);
          bf16x8 w1 = *(const bf16x8*)(pw1 + kc * 512);
          if (kc & 1) { zb = MFMA(a, w0, zb); yb = MFMA(a, w1, yb); }
          else        { za = MFMA(a, w0, za); ya = MFMA(a, w1, ya); }
        }
        if (t >= 2) {
#pragma unroll
          for (int kc = 0; kc < 16; ++kc) {
            bf16x8 a = *(const bf16x8*)(afrag1 + kc * 68);
            if (kc & 1) yb = MFMA(a, whh1f[kc], yb);
            else        ya = MFMA(a, whh1f[kc], ya);
          }
        }
        actstore(za + zb, c0, h0cur, tg0);
        actstore(ya + yb, c1, h1cur, tg1);
      } else {
        actstore(za + zb, c0, h0cur, tg0);
      }
    } else {                                   // t == Tt: final layer1 step
      f32x4 ya = {b1c, b1c, b1c, b1c}, yb = {0.f, 0.f, 0.f, 0.f};
#pragma unroll
      for (int kc = 0; kc < 16; ++kc) {
        bf16x8 a = *(const bf16x8*)(afrag0 + kc * 68);
        bf16x8 w1 = *(const bf16x8*)(pw1 + kc * 512);
        if (kc & 1) yb = MFMA(a, w1, yb);
        else        ya = MFMA(a, w1, ya);
      }
#pragma unroll
      for (int kc = 0; kc < 16; ++kc) {
        bf16x8 a = *(const bf16x8*)(afrag1 + kc * 68);
        if (kc & 1) yb = MFMA(a, whh1f[kc], yb);
        else        ya = MFMA(a, whh1f[kc], ya);
      }
      actstore(ya + yb, c1, h1cur, tg1);
    }
  }

  // ============ decoder: d = 0..95, 2 phases/step, tags continue ============
  // h0/h1 phase 512+d: slot (2+d)%3, tag (d+1)&3.
  for (int d = 0; d < TGT; ++d) {
    // ---- phase A: layer0 (+ fc of previous step via staged h1) ----
    {
      bf16x8 xa0, xa1;
      if (d == 0) {
        const float* xb = x + (size_t)(g * 8 + (col & 7)) * xstride + (size_t)(Tt - 1) * 64 + koff;
        xa0 = loadx(xb); xa1 = loadx(xb + 32);
      }
      wgbar();
      pollstage2(sm.a0, h0q + ((1 + d) % 3) * 8192 + gbase, (unsigned)(d & 3),
                 sm.a1, h1q + ((1 + d) % 3) * 8192 + gbase, (unsigned)(d & 3), tid);
      wgbar();
      if (d) fcpart(sm.a1);                   // y_{d-1} partials from h1_{511+d}
      f32x4 za, zb = {0.f, 0.f, 0.f, 0.f};
      if (d == 0) {
        za = (f32x4){b0c, b0c, b0c, b0c};
        za = MFMA(xa0, wih0f[0], za);
        zb = MFMA(xa1, wih0f[1], zb);
#pragma unroll
        for (int kc = 0; kc < 16; ++kc) {
          bf16x8 a = *(const bf16x8*)(afrag0 + kc * 68);
          bf16x8 w0 = *(const bf16x8*)(pw0 + kc * 512);
          if (kc & 1) zb = MFMA(a, w0, zb);
          else        za = MFMA(a, w0, za);
        }
      } else {
        za = (f32x4){b0dc, b0dc, b0dc, b0dc};
#pragma unroll
        for (int kc = 0; kc < 16; ++kc) {
          bf16x8 a = *(const bf16x8*)(afrag0 + kc * 68);
          bf16x8 w0 = *(const bf16x8*)(pw0 + kc * 512);
          bf16x8 a2 = *(const bf16x8*)(afrag1 + kc * 68);
          if (kc & 1) { zb = MFMA(a, w0, zb); zb = MFMA(a2, wcombf[kc], zb); }
          else        { za = MFMA(a, w0, za); za = MFMA(a2, wcombf[kc], za); }
        }
      }
      actstore(za + zb, c0, h0q + ((2 + d) % 3) * 8192 + gbase, (unsigned)((d + 1) & 3));
      if (d) { wgbar(); fcout(d - 1); }
    }

    // ---- phase B: layer1 (a1 still holds h1_{511+d}) ----
    {
      wgbar();
      pollstage1(sm.a0, h0q + ((2 + d) % 3) * 8192 + gbase, (unsigned)((d + 1) & 3), tid);
      wgbar();
      f32x4 ya = {b1c, b1c, b1c, b1c}, yb = {0.f, 0.f, 0.f, 0.f};
#pragma unroll
      for (int kc = 0; kc < 16; ++kc) {
        bf16x8 a = *(const bf16x8*)(afrag0 + kc * 68);
        bf16x8 w1 = *(const bf16x8*)(pw1 + kc * 512);
        bf16x8 a2 = *(const bf16x8*)(afrag1 + kc * 68);
        if (kc & 1) { yb = MFMA(a, w1, yb); yb = MFMA(a2, whh1f[kc], yb); }
        else        { ya = MFMA(a, w1, ya); ya = MFMA(a2, whh1f[kc], ya); }
      }
      actstore(ya + yb, c1, h1q + ((2 + d) % 3) * 8192 + gbase, (unsigned)((d + 1) & 3));
    }
  }

  // ---- final fc: out[95] from h1_607 (slot (2+95)%3 = 1, tag 0) ----
  {
    wgbar();
    pollstage1(sm.a1, h1q + 1 * 8192 + gbase, 0u, tid);
    wgbar();
    fcpart(sm.a1);
    wgbar();
    fcout(TGT - 1);
  }
}

extern "C" void kernel_launch(void* const* d_in, const int* in_sizes, int n_in,
                              void* d_out, int out_size, void* d_ws, size_t ws_size,
                              hipStream_t stream) {
  (void)in_sizes; (void)n_in; (void)out_size; (void)ws_size;
  const float* x    = (const float*)d_in[0];
  const float* Wih0 = (const float*)d_in[1];
  const float* Whh0 = (const float*)d_in[2];
  const float* bih0 = (const float*)d_in[3];
  const float* bhh0 = (const float*)d_in[4];
  const float* Wih1 = (const float*)d_in[5];
  const float* Whh1 = (const float*)d_in[6];
  const float* bih1 = (const float*)d_in[7];
  const float* bhh1 = (const float*)d_in[8];
  const float* Wfc  = (const float*)d_in[9];
  const float* bfc  = (const float*)d_in[10];

  char* ws = (char*)d_ws;
  u64* h0q = (u64*)ws;                   // 3 slots x 8 groups x 1024 u64 = 192 KiB
  u64* h1q = (u64*)(ws + 196608);        // 192 KiB

  // deterministic poison (tag 0) so first-use polls can't false-accept
  hipMemsetAsync(ws, 0xAA, 393216, stream);
  hipLaunchKernelGGL(lstm_kernel, dim3(NWG), dim3(NTH), 0, stream,
                     x, Wih0, Whh0, bih0, bhh0, Wih1, Whh1, bih1, bhh1, Wfc, bfc,
                     h0q, h1q, (float*)d_out);
}